// Round 2
// baseline (385.157 us; speedup 1.0000x reference)
//
#include <hip/hip_runtime.h>
#include <math.h>

// GraphPyramidPooling: the adjacency g is dead code w.r.t. the output (it only
// feeds the next level's adjacency, never h or the unpool). The output is
//   out[node]  += h[node]  * s0[node]            for node in top-K0 of s0
//   out[rank0] += h[g0]    * s0[g0]*s1[rank0]    for rank0 in top-K1 of s1
//   out[rank1] += h[g0']   * s0*s1*s2 composed   for rank1 in top-K2 of s2
// where s1 is computed on gathered/gated rows: dot(h1[r],W1) = s0[g]*dot(h[g],W1),
// so everything reduces to 3 fp64 dot passes + scalar score composition + ranks.
//
// Static sizes: N0=4096, D=512; k levels: int(0.8*4096)=3276,
// int(0.6*3276)=1965, int(0.4*1965)=786.

#define N0 4096
#define K0 3276
#define K1 1965
#define K2 786
#define DD 512

// ---- one 64-lane wave per row: all three dots in fp64 (exact ordering) ----
__global__ void gpp_dots(const float* __restrict__ h, const float* __restrict__ W,
                         const float* __restrict__ b,
                         double* __restrict__ s0, double* __restrict__ d1,
                         double* __restrict__ d2) {
    int row  = (int)((blockIdx.x * blockDim.x + threadIdx.x) >> 6);
    int lane = (int)(threadIdx.x & 63);
    if (row >= N0) return;
    const float* hr = h + (size_t)row * DD;
    double a0 = 0.0, a1 = 0.0, a2 = 0.0;
#pragma unroll
    for (int i = 0; i < DD / 64; ++i) {
        int d = lane + i * 64;
        double hv = (double)hr[d];
        a0 += hv * (double)W[d];
        a1 += hv * (double)W[DD + d];
        a2 += hv * (double)W[2 * DD + d];
    }
#pragma unroll
    for (int off = 32; off >= 1; off >>= 1) {
        a0 += __shfl_xor(a0, off, 64);
        a1 += __shfl_xor(a1, off, 64);
        a2 += __shfl_xor(a2, off, 64);
    }
    if (lane == 0) {
        s0[row] = 1.0 / (1.0 + exp(-(a0 + (double)b[0])));  // sigmoid fp64
        d1[row] = a1;
        d2[row] = a2;
    }
}

// ---- rank by counting: order[rank(i)] = i; desc, tie -> lower index first ----
// Matches lax.top_k tie semantics. O(n^2) compares, all from LDS.
__global__ void gpp_rank(const double* __restrict__ sc, int n, int* __restrict__ order) {
    __shared__ double s_sc[N0];
    for (int j = (int)threadIdx.x; j < n; j += (int)blockDim.x) s_sc[j] = sc[j];
    __syncthreads();
    int i = (int)(blockIdx.x * blockDim.x + threadIdx.x);
    if (i >= n) return;
    double si = s_sc[i];
    int cnt = 0;
    for (int j = 0; j < n; ++j) {
        double sj = s_sc[j];
        cnt += (int)((sj > si) | ((sj == si) & (j < i)));
    }
    order[cnt] = i;
}

// ---- score composition (tiny) ----
__global__ void gpp_s1(const double* __restrict__ s0, const double* __restrict__ d1,
                       const float* __restrict__ b, const int* __restrict__ ord0,
                       double* __restrict__ s1) {
    int r = (int)(blockIdx.x * blockDim.x + threadIdx.x);
    if (r >= K0) return;
    int g = ord0[r];
    double z = s0[g] * d1[g] + (double)b[1];
    s1[r] = 1.0 / (1.0 + exp(-z));
}

__global__ void gpp_s2(const double* __restrict__ s0, const double* __restrict__ s1,
                       const double* __restrict__ d2, const float* __restrict__ b,
                       const int* __restrict__ ord0, const int* __restrict__ ord1,
                       double* __restrict__ s2) {
    int r = (int)(blockIdx.x * blockDim.x + threadIdx.x);
    if (r >= K1) return;
    int g1 = ord1[r];
    int g0 = ord0[g1];
    double z = s1[g1] * s0[g0] * d2[g0] + (double)b[2];
    s2[r] = 1.0 / (1.0 + exp(-z));
}

// ---- scatter one selected row: out[row] += h[src] * gate ----
// lvl 0: src=row=node id.  lvl 1: row=rank in level-0 order, src=ord0[row].
// lvl 2: row=rank in level-1 order, src=ord0[ord1[row]].
// Rows are distinct within a level; kernels are stream-ordered across levels.
__global__ void gpp_scatter(const float* __restrict__ h, const double* __restrict__ s0,
                            const double* __restrict__ s1, const double* __restrict__ s2,
                            const int* __restrict__ ord0, const int* __restrict__ ord1,
                            const int* __restrict__ ord2, int lvl,
                            float* __restrict__ out) {
    int j = (int)blockIdx.x;
    int src, row;
    float gate;
    if (lvl == 0) {
        src = ord0[j]; row = src;
        gate = (float)s0[src];
    } else if (lvl == 1) {
        int r = ord1[j]; int g = ord0[r];
        src = g; row = r;
        gate = (float)(s0[g] * s1[r]);
    } else {
        int r = ord2[j]; int g1 = ord1[r]; int g0 = ord0[g1];
        src = g0; row = r;
        gate = (float)(s0[g0] * s1[g1] * s2[r]);
    }
    const float4* srcp = (const float4*)(h + (size_t)src * DD);
    float4*       outp = (float4*)(out + (size_t)row * DD);
    int t = (int)threadIdx.x;  // blockDim = 128 -> 128 * float4 = 512 floats
    float4 v = srcp[t];
    float4 o = outp[t];
    o.x += v.x * gate; o.y += v.y * gate; o.z += v.z * gate; o.w += v.w * gate;
    outp[t] = o;
}

extern "C" void kernel_launch(void* const* d_in, const int* in_sizes, int n_in,
                              void* d_out, int out_size, void* d_ws, size_t ws_size,
                              hipStream_t stream) {
    // inputs: d_in[0]=g (UNUSED), d_in[1]=h [4096,512], d_in[2]=W [3,512], d_in[3]=b [3]
    const float* h = (const float*)d_in[1];
    const float* W = (const float*)d_in[2];
    const float* b = (const float*)d_in[3];
    float* out = (float*)d_out;

    // workspace layout (~178 KB total; doubles first for 8B alignment)
    char* ws = (char*)d_ws;
    double* s0 = (double*)(ws);                                   // 4096*8 = 32768
    double* d1 = (double*)(ws + 32768);                           // 32768
    double* d2 = (double*)(ws + 65536);                           // 32768
    double* s1 = (double*)(ws + 98304);                           // K0*8 = 26208
    double* s2 = (double*)(ws + 124512);                          // K1*8 = 15720
    int* ord0  = (int*)(ws + 140232);                             // 4096*4 = 16384
    int* ord1  = (int*)(ws + 156616);                             // K0*4 = 13104
    int* ord2  = (int*)(ws + 169720);                             // K1*4 = 7860  -> 177580 total

    // out is re-poisoned before every timed call: zero it
    hipMemsetAsync(d_out, 0, (size_t)N0 * DD * sizeof(float), stream);

    gpp_dots<<<(N0 * 64) / 256, 256, 0, stream>>>(h, W, b, s0, d1, d2);

    gpp_rank<<<(N0 + 255) / 256, 256, 0, stream>>>(s0, N0, ord0);
    gpp_s1<<<(K0 + 255) / 256, 256, 0, stream>>>(s0, d1, b, ord0, s1);
    gpp_rank<<<(K0 + 255) / 256, 256, 0, stream>>>(s1, K0, ord1);
    gpp_s2<<<(K1 + 255) / 256, 256, 0, stream>>>(s0, s1, d2, b, ord0, ord1, s2);
    gpp_rank<<<(K1 + 255) / 256, 256, 0, stream>>>(s2, K1, ord2);

    gpp_scatter<<<K0, 128, 0, stream>>>(h, s0, s1, s2, ord0, ord1, ord2, 0, out);
    gpp_scatter<<<K1, 128, 0, stream>>>(h, s0, s1, s2, ord0, ord1, ord2, 1, out);
    gpp_scatter<<<K2, 128, 0, stream>>>(h, s0, s1, s2, ord0, ord1, ord2, 2, out);
}

// Round 3
// 143.298 us; speedup vs baseline: 2.6878x; 2.6878x over previous
//
#include <hip/hip_runtime.h>
#include <math.h>

// GraphPyramidPooling: adjacency g is dead code w.r.t. the output. Pipeline:
//   fp64 dots (3 per row) -> rank0 -> s1 -> rank1 -> s2 -> rank2 -> one scatter.
// Ranks via 2D-tiled counting (desc, tie -> lower index first, = lax.top_k).
// Place kernels fuse next-level score composition and per-row output gates so
// the final scatter is a single write-only pass over all N0 rows (no memset of
// d_out, no read-modify-write).
//
// Static sizes: N0=4096, D=512; int(0.8*4096)=3276, int(0.6*3276)=1965,
// int(0.4*1965)=786.

#define N0 4096
#define K0 3276
#define K1 1965
#define K2 786
#define DD 512
#define TJ 256

// ---- one 64-lane wave per row: all three dots in fp64 (exact ordering) ----
__global__ void gpp_dots(const float* __restrict__ h, const float* __restrict__ W,
                         const float* __restrict__ b,
                         double* __restrict__ s0, double* __restrict__ d1,
                         double* __restrict__ d2) {
    int row  = (int)((blockIdx.x * blockDim.x + threadIdx.x) >> 6);
    int lane = (int)(threadIdx.x & 63);
    if (row >= N0) return;
    const float* hr = h + (size_t)row * DD;
    double a0 = 0.0, a1 = 0.0, a2 = 0.0;
#pragma unroll
    for (int i = 0; i < DD / 64; ++i) {
        int d = lane + i * 64;
        double hv = (double)hr[d];
        a0 += hv * (double)W[d];
        a1 += hv * (double)W[DD + d];
        a2 += hv * (double)W[2 * DD + d];
    }
#pragma unroll
    for (int off = 32; off >= 1; off >>= 1) {
        a0 += __shfl_xor(a0, off, 64);
        a1 += __shfl_xor(a1, off, 64);
        a2 += __shfl_xor(a2, off, 64);
    }
    if (lane == 0) {
        s0[row] = 1.0 / (1.0 + exp(-(a0 + (double)b[0])));  // sigmoid fp64
        d1[row] = a1;
        d2[row] = a2;
    }
}

// ---- 2D-tiled rank counting: cnt[i] += #{j in tile : s[j]>s[i] or tie,j<i} ----
__global__ void gpp_count(const double* __restrict__ sc, int n, int* __restrict__ cnt) {
    __shared__ double s_sc[TJ];
    int tid = (int)threadIdx.x;
    int j0 = (int)blockIdx.y * TJ;
    int jmax = n - j0; if (jmax > TJ) jmax = TJ;
    if (tid < jmax) s_sc[tid] = sc[j0 + tid];
    __syncthreads();
    int i = (int)blockIdx.x * 256 + tid;
    if (i >= n) return;
    double si = sc[i];
    int c = 0;
#pragma unroll 8
    for (int j = 0; j < jmax; ++j) {
        double sj = s_sc[j];
        c += (int)((sj > si) | ((sj == si) & (j0 + j < i)));
    }
    if (c) atomicAdd(&cnt[i], c);
}

// ---- place level 0: ord0[rank]=i, gateA[i], and s1[rank] for selected ----
__global__ void gpp_place0(const int* __restrict__ cnt0, const double* __restrict__ s0,
                           const double* __restrict__ d1, const float* __restrict__ b,
                           int* __restrict__ ord0, float* __restrict__ gateA,
                           double* __restrict__ s1) {
    int i = (int)(blockIdx.x * blockDim.x + threadIdx.x);
    if (i >= N0) return;
    int r = cnt0[i];
    ord0[r] = i;
    bool sel = r < K0;
    gateA[i] = sel ? (float)s0[i] : 0.0f;
    if (sel) {
        double z = s0[i] * d1[i] + (double)b[1];
        s1[r] = 1.0 / (1.0 + exp(-z));
    }
}

// ---- place level 1: ord1[rank]=r, gateB[r], and s2[rank] for selected ----
__global__ void gpp_place1(const int* __restrict__ cnt1, const double* __restrict__ s0,
                           const double* __restrict__ s1, const double* __restrict__ d2,
                           const float* __restrict__ b, const int* __restrict__ ord0,
                           int* __restrict__ ord1, float* __restrict__ gateB,
                           double* __restrict__ s2) {
    int r = (int)(blockIdx.x * blockDim.x + threadIdx.x);
    if (r >= K0) return;
    int r1 = cnt1[r];
    ord1[r1] = r;
    int g = ord0[r];
    bool sel = r1 < K1;
    gateB[r] = sel ? (float)(s0[g] * s1[r]) : 0.0f;
    if (sel) {
        double z = s1[r] * s0[g] * d2[g] + (double)b[2];
        s2[r1] = 1.0 / (1.0 + exp(-z));
    }
}

// ---- place level 2: gateC[r] + composed source srcC[r] ----
__global__ void gpp_place2(const int* __restrict__ cnt2, const double* __restrict__ s0,
                           const double* __restrict__ s1, const double* __restrict__ s2,
                           const int* __restrict__ ord0, const int* __restrict__ ord1,
                           float* __restrict__ gateC, int* __restrict__ srcC) {
    int r = (int)(blockIdx.x * blockDim.x + threadIdx.x);
    if (r >= K1) return;
    int r2 = cnt2[r];
    int g1 = ord1[r];
    int g0 = ord0[g1];
    bool sel = r2 < K2;
    gateC[r] = sel ? (float)(s0[g0] * s1[g1] * s2[r]) : 0.0f;
    srcC[r] = g0;
}

// ---- single write-only scatter over all rows ----
// out[i] = h[i]*gateA[i] + (i<K0 ? h[ord0[i]]*gateB[i] : 0)
//                        + (i<K1 ? h[srcC[i]]*gateC[i] : 0)
__global__ void gpp_scatter(const float* __restrict__ h, const float* __restrict__ gateA,
                            const float* __restrict__ gateB, const float* __restrict__ gateC,
                            const int* __restrict__ ord0, const int* __restrict__ srcC,
                            float* __restrict__ out) {
    int i = (int)blockIdx.x;
    int t = (int)threadIdx.x;  // blockDim = 128 -> 128 * float4 = 512 floats
    float ga = gateA[i];
    const float4* pa = (const float4*)(h + (size_t)i * DD);
    float4 v = pa[t];
    float4 o;
    o.x = v.x * ga; o.y = v.y * ga; o.z = v.z * ga; o.w = v.w * ga;
    if (i < K0) {
        float gb = gateB[i];
        const float4* pb = (const float4*)(h + (size_t)ord0[i] * DD);
        float4 vb = pb[t];
        o.x += vb.x * gb; o.y += vb.y * gb; o.z += vb.z * gb; o.w += vb.w * gb;
    }
    if (i < K1) {
        float gc = gateC[i];
        const float4* pc = (const float4*)(h + (size_t)srcC[i] * DD);
        float4 vc = pc[t];
        o.x += vc.x * gc; o.y += vc.y * gc; o.z += vc.z * gc; o.w += vc.w * gc;
    }
    float4* po = (float4*)(out + (size_t)i * DD);
    po[t] = o;
}

extern "C" void kernel_launch(void* const* d_in, const int* in_sizes, int n_in,
                              void* d_out, int out_size, void* d_ws, size_t ws_size,
                              hipStream_t stream) {
    // inputs: d_in[0]=g (UNUSED), d_in[1]=h [4096,512], d_in[2]=W [3,512], d_in[3]=b [3]
    const float* h = (const float*)d_in[1];
    const float* W = (const float*)d_in[2];
    const float* b = (const float*)d_in[3];
    float* out = (float*)d_out;

    // workspace layout (~247 KB; doubles first for 8B alignment)
    char* ws = (char*)d_ws;
    double* s0   = (double*)(ws);                   // 4096*8 = 32768
    double* d1   = (double*)(ws + 32768);           // 32768
    double* d2   = (double*)(ws + 65536);           // 32768
    double* s1   = (double*)(ws + 98304);           // K0*8 = 26208
    double* s2   = (double*)(ws + 124512);          // K1*8 = 15720 -> 140232
    int*   cnt0  = (int*)(ws + 140232);             // 16384
    int*   cnt1  = (int*)(ws + 156616);             // 13104
    int*   cnt2  = (int*)(ws + 169720);             // 7860  -> 177580
    int*   ord0  = (int*)(ws + 177580);             // 16384
    int*   ord1  = (int*)(ws + 193964);             // 13104 -> 207068
    float* gateA = (float*)(ws + 207068);           // 16384
    float* gateB = (float*)(ws + 223452);           // 13104
    float* gateC = (float*)(ws + 236556);           // 7860
    int*   srcC  = (int*)(ws + 244416);             // 7860  -> 252276

    // zero the three count buffers (contiguous region)
    hipMemsetAsync(ws + 140232, 0, 177580 - 140232, stream);

    gpp_dots<<<(N0 * 64) / 256, 256, 0, stream>>>(h, W, b, s0, d1, d2);

    dim3 c0((N0 + 255) / 256, (N0 + TJ - 1) / TJ);
    gpp_count<<<c0, 256, 0, stream>>>(s0, N0, cnt0);
    gpp_place0<<<(N0 + 255) / 256, 256, 0, stream>>>(cnt0, s0, d1, b, ord0, gateA, s1);

    dim3 c1((K0 + 255) / 256, (K0 + TJ - 1) / TJ);
    gpp_count<<<c1, 256, 0, stream>>>(s1, K0, cnt1);
    gpp_place1<<<(K0 + 255) / 256, 256, 0, stream>>>(cnt1, s0, s1, d2, b, ord0, ord1, gateB, s2);

    dim3 c2((K1 + 255) / 256, (K1 + TJ - 1) / TJ);
    gpp_count<<<c2, 256, 0, stream>>>(s2, K1, cnt2);
    gpp_place2<<<(K1 + 255) / 256, 256, 0, stream>>>(cnt2, s0, s1, s2, ord0, ord1, gateC, srcC);

    gpp_scatter<<<N0, 128, 0, stream>>>(h, gateA, gateB, gateC, ord0, srcC, out);
}